// Round 8
// baseline (501.233 us; speedup 1.0000x reference)
//
#include <hip/hip_runtime.h>
#include <hip/hip_bf16.h>

#define DEV __device__ __forceinline__

typedef __attribute__((ext_vector_type(8))) short bf16x8;
typedef __attribute__((ext_vector_type(4))) float f32x4;

DEV float bf2f(__hip_bfloat16 v) { return __bfloat162float(v); }
DEV float b2f(short u) { return __uint_as_float(((unsigned)(unsigned short)u) << 16); }
DEV float lrelu(float x) { return x > 0.f ? x : 0.2f * x; }
DEV float eluf(float x) { return x > 0.f ? x : (__expf(x) - 1.f); }

// fp32 -> bf16 bits, round-to-nearest-even
DEV unsigned short f2bf(float x) {
    unsigned int u = __float_as_uint(x);
    return (unsigned short)((u + 0x7FFFu + ((u >> 16) & 1u)) >> 16);
}

// Read element i of a float tensor that is either bf16 (f=1) or fp32 (f=0).
DEV float ldf(const void* p, int i, int f) {
    return f ? bf2f(((const __hip_bfloat16*)p)[i]) : ((const float*)p)[i];
}

// Inline dtype detection (see r2 notes): bf16 low-half exponent test, 64 samples.
DEV int detect_bf16(const void* p) {
    const unsigned int* w = (const unsigned int*)p;
    unsigned int e = (w[threadIdx.x & 63] >> 7) & 0xFFu;
    int hit = (e >= 112u && e <= 130u) ? 1 : 0;
    unsigned long long b = __ballot(hit);
    return __popcll(b) > 32 ? 1 : 0;
}

// Load 8 consecutive "float" elems as 8 packed bf16 (16B).
// mode==0: src is our own bf16 buffer. mode==1: raw input, branch on f.
DEV uint4 ld8(const void* src, size_t off, int mode, int f) {
    if (mode == 0 || f) return *(const uint4*)((const unsigned short*)src + off);
    const float* s = (const float*)src + off;
    float4 a = *(const float4*)s, b = *(const float4*)(s + 4);
    uint4 r;
    r.x = f2bf(a.x) | ((unsigned)f2bf(a.y) << 16);
    r.y = f2bf(a.z) | ((unsigned)f2bf(a.w) << 16);
    r.z = f2bf(b.x) | ((unsigned)f2bf(b.y) << 16);
    r.w = f2bf(b.z) | ((unsigned)f2bf(b.w) << 16);
    return r;
}

// ---------------- param conversion ----------------

struct Ptrs15 { const void* p[15]; };  // [14] = x1 (for detection)

#define P_W0 0
#define P_W1 4096
#define P_W2 12288
#define P_AS0 14336
#define P_AD0 14400
#define P_B0 14464
#define P_AS1 14528
#define P_AD1 14592
#define P_B1 14656
#define P_AS2 14720
#define P_AD2 14736
#define P_B2 14752
#define P_GAMMA 14768
#define P_BETA 14784
#define P_TOTAL 14800

__global__ void k_params(Ptrs15 pp, float* __restrict__ P) {
    const int narr[14] = {4096, 8192, 2048, 64, 64, 64, 64, 64, 64, 16, 16, 16, 16, 16};
    const int oarr[14] = {P_W0, P_W1, P_W2, P_AS0, P_AD0, P_B0, P_AS1, P_AD1, P_B1,
                          P_AS2, P_AD2, P_B2, P_GAMMA, P_BETA};
    int f = detect_bf16(pp.p[14]);
    int b = blockIdx.x;
    const void* src = pp.p[b];
    int nn = narr[b], oo = oarr[b];
    for (int i = threadIdx.x; i < nn; i += blockDim.x)
        P[oo + i] = ldf(src, i, f);
}

// ---------------- CSR build: contention-free 3-phase bucket sort ----------------
// bedge entry packs (src<<8)|(dst&255): src < 2^17, fits 25 bits.

#define CAP 6144
#define NBLK 512
#define NBMAX 1024

__global__ __launch_bounds__(256) void k_count(
    const int* __restrict__ ei1, const int* __restrict__ ei2, int E,
    int* __restrict__ counts, int nb, int NB, int chunk)
{
    __shared__ int lcnt[NBMAX];
    int t = threadIdx.x, blk = blockIdx.x;
    for (int b = t; b < NB; b += 256) lcnt[b] = 0;
    __syncthreads();
    int i0 = blk * chunk, i1 = min(i0 + chunk, 2 * E);
    for (int i = i0 + t; i < i1; i += 256) {
        int b;
        if (i < E) b = ei1[E + i] >> 8;
        else       b = (ei2[i] >> 8) + nb;
        atomicAdd(&lcnt[b], 1);
    }
    __syncthreads();
    for (int b = t; b < NB; b += 256) counts[b * NBLK + blk] = lcnt[b];
}

__global__ __launch_bounds__(256) void k_scan(
    int* __restrict__ counts, int* __restrict__ bfill)
{
    int b = blockIdx.x, t = threadIdx.x;
    __shared__ int ps[256];
    int* row = counts + b * NBLK;
    int x0 = row[2 * t], x1 = row[2 * t + 1];
    ps[t] = x0 + x1;
    __syncthreads();
    #pragma unroll
    for (int off = 1; off < 256; off <<= 1) {
        int v = (t >= off) ? ps[t - off] : 0;
        __syncthreads();
        ps[t] += v;
        __syncthreads();
    }
    int excl = ps[t] - (x0 + x1);
    row[2 * t] = excl;
    row[2 * t + 1] = excl + x0;
    if (t == 255) bfill[b] = ps[255];
}

__global__ __launch_bounds__(256) void k_place(
    const int* __restrict__ ei1, const int* __restrict__ ei2, int E,
    const int* __restrict__ counts, int* __restrict__ bedge,
    int nb, int NB, int chunk)
{
    __shared__ int lbase[NBMAX];
    int t = threadIdx.x, blk = blockIdx.x;
    for (int b = t; b < NB; b += 256) lbase[b] = counts[b * NBLK + blk];
    __syncthreads();
    int i0 = blk * chunk, i1 = min(i0 + chunk, 2 * E);
    for (int i = i0 + t; i < i1; i += 256) {
        int s, d, b;
        if (i < E) { s = ei1[i]; d = ei1[E + i]; b = d >> 8; }
        else       { s = ei2[i - E]; d = ei2[i]; b = (d >> 8) + nb; }
        int pos = atomicAdd(&lbase[b], 1);
        if (pos < CAP) bedge[(size_t)b * CAP + pos] = (s << 8) | (d & 255);
    }
}

__global__ __launch_bounds__(256) void k_bucket2(
    const int* __restrict__ bfill1, const int* __restrict__ bedge1,
    int* __restrict__ rp1, int* __restrict__ dg1, int* __restrict__ col1,
    const int* __restrict__ bfill2, const int* __restrict__ bedge2,
    int* __restrict__ rp2, int* __restrict__ dg2, int* __restrict__ col2,
    int nb, int N)
{
    int b = blockIdx.x;
    const int* bfill; const int* bedge; int* rowptr; int* deg; int* col;
    if (b < nb) { bfill = bfill1; bedge = bedge1; rowptr = rp1; deg = dg1; col = col1; }
    else { b -= nb; bfill = bfill2; bedge = bedge2; rowptr = rp2; deg = dg2; col = col2; }

    __shared__ int ldeg[256], lscan[256], lfill[256];
    int t = threadIdx.x;
    ldeg[t] = 0;
    __syncthreads();

    int cnt = min(bfill[b], CAP);
    const int* be = bedge + (size_t)b * CAP;
    for (int e = t; e < cnt; e += 256) atomicAdd(&ldeg[be[e] & 255], 1);
    __syncthreads();

    int myDeg = ldeg[t];
    lscan[t] = myDeg;
    __syncthreads();
    #pragma unroll
    for (int off = 1; off < 256; off <<= 1) {
        int v = (t >= off) ? lscan[t - off] : 0;
        __syncthreads();
        lscan[t] += v;
        __syncthreads();
    }
    int excl = lscan[t] - myDeg;
    int node = (b << 8) + t;
    int base = b * CAP;
    if (node < N) { rowptr[node] = base + excl; deg[node] = myDeg; }
    lfill[t] = excl;
    __syncthreads();

    for (int e = t; e < cnt; e += 256) {
        int ed = be[e];
        int pos = atomicAdd(&lfill[ed & 255], 1);
        col[base + pos] = ed >> 8;     // src (logical: s<2^24, packed unsigned-safe)
    }
}

// ---------------- MFMA bf16 GEMM; Hout is BF16 now ----------------

template <int K, int C>
__global__ __launch_bounds__(256) void k_gemm_mfma(
    const void* __restrict__ A1, int mode1, const void* __restrict__ A2, int mode2,
    const float* __restrict__ W, const float* __restrict__ av, const float* __restrict__ dv,
    unsigned short* __restrict__ Hout, float* __restrict__ as_, float* __restrict__ ad_,
    int N, int numTiles)
{
    constexpr int KP = K + 8;
    constexpr int KK = K / 32;
    constexpr int CT = C / 16;
    constexpr int G  = K / 8;

    __shared__ alignas(16) short As[64 * KP];
    __shared__ alignas(16) short Wt[C * KP];
    __shared__ float avs[C], dvs[C];

    int t = threadIdx.x;
    int f = 0;
    if (mode1) f = detect_bf16(A1);
    else if (mode2) f = detect_bf16(A2);

    for (int idx = t; idx < K * C; idx += 256) {
        int k = idx / C, n = idx % C;
        Wt[n * KP + k] = (short)f2bf(W[idx]);
    }
    for (int i = t; i < C; i += 256) { avs[i] = av[i]; dvs[i] = dv[i]; }
    __syncthreads();

    const int lane = t & 63, w = t >> 6;
    const int m = lane & 15, q = lane >> 4;

    bf16x8 bfr[KK][CT];
    #pragma unroll
    for (int kk = 0; kk < KK; kk++)
        #pragma unroll
        for (int ct = 0; ct < CT; ct++)
            bfr[kk][ct] = *(const bf16x8*)&Wt[(ct * 16 + m) * KP + kk * 32 + q * 8];

    for (int tile = blockIdx.x; tile < numTiles; tile += gridDim.x) {
        __syncthreads();
        int rowBase = tile * 64;
        for (int idx = t; idx < 64 * G; idx += 256) {
            int r = idx / G, g = idx % G;
            int row = rowBase + r;
            uint4 val = {0u, 0u, 0u, 0u};
            if (row < N) {
                if (g < 8) val = ld8(A1, (size_t)row * 64 + g * 8, mode1, f);
                else       val = ld8(A2, (size_t)row * 64 + (g - 8) * 8, mode2, f);
            }
            *(uint4*)&As[r * KP + g * 8] = val;
        }
        __syncthreads();

        f32x4 acc[CT];
        #pragma unroll
        for (int ct = 0; ct < CT; ct++) acc[ct] = (f32x4){0.f, 0.f, 0.f, 0.f};

        #pragma unroll
        for (int kk = 0; kk < KK; kk++) {
            bf16x8 a = *(const bf16x8*)&As[(w * 16 + m) * KP + kk * 32 + q * 8];
            #pragma unroll
            for (int ct = 0; ct < CT; ct++)
                acc[ct] = __builtin_amdgcn_mfma_f32_16x16x32_bf16(a, bfr[kk][ct], acc[ct], 0, 0, 0);
        }

        #pragma unroll
        for (int r = 0; r < 4; r++) {
            int grow = rowBase + w * 16 + q * 4 + r;
            float vs = 0.f, vd = 0.f;
            #pragma unroll
            for (int ct = 0; ct < CT; ct++) {
                float v = acc[ct][r];
                vs += v * avs[ct * 16 + m];
                vd += v * dvs[ct * 16 + m];
                if (grow < N) Hout[(size_t)grow * C + ct * 16 + m] = f2bf(v);
            }
            vs += __shfl_xor(vs, 1); vs += __shfl_xor(vs, 2);
            vs += __shfl_xor(vs, 4); vs += __shfl_xor(vs, 8);
            vd += __shfl_xor(vd, 1); vd += __shfl_xor(vd, 2);
            vd += __shfl_xor(vd, 4); vd += __shfl_xor(vd, 8);
            if (grow < N && m == 0) { as_[grow] = vs; ad_[grow] = vd; }
        }
    }
}

// ---------------- Aggregation F=64: bf16 gather, 8 lanes/row x 8 edge groups ----------------

__global__ __launch_bounds__(256) void k_agg64(
    const int* __restrict__ rowptr, const int* __restrict__ deg,
    const int* __restrict__ col, const float* __restrict__ as_,
    const float* __restrict__ ad_, const unsigned short* __restrict__ h,
    const float* __restrict__ bias, unsigned short* __restrict__ out,
    int N, int doElu)
{
    int wid = (blockIdx.x * blockDim.x + threadIdx.x) >> 6;
    int lane = threadIdx.x & 63;
    if (wid >= N) return;
    int start = rowptr[wid];
    int d = deg[wid];
    float adi = ad_[wid];
    float eself = __expf(lrelu(as_[wid] + adi));

    int dc = min(d, 64);
    float w = 0.f; int s = 0;
    if (lane < dc) { s = col[start + lane]; w = __expf(lrelu(as_[s] + adi)); }
    float ssum = w;
    for (int j = lane + 64; j < d; j += 64)
        ssum += __expf(lrelu(as_[col[start + j]] + adi));
    #pragma unroll
    for (int off = 32; off; off >>= 1) ssum += __shfl_xor(ssum, off);
    float inv = 1.f / (ssum + eself + 1e-16f);
    w *= inv;

    int fq = lane & 7, eg = lane >> 3;
    float acc[8] = {0.f, 0.f, 0.f, 0.f, 0.f, 0.f, 0.f, 0.f};
    if (eg == 0) {
        bf16x8 hv = *(const bf16x8*)&h[(size_t)wid * 64 + fq * 8];
        float en = eself * inv;
        #pragma unroll
        for (int i = 0; i < 8; i++) acc[i] = en * b2f(hv[i]);
    }
    {
        int iters = (dc + 7) >> 3;
        for (int it = 0; it < iters; it++) {
            int j = it * 8 + eg;
            float wj = __shfl(w, j);
            int sj = __shfl(s, j);
            if (j < dc) {
                bf16x8 hv = *(const bf16x8*)&h[(size_t)sj * 64 + fq * 8];
                #pragma unroll
                for (int i = 0; i < 8; i++) acc[i] += wj * b2f(hv[i]);
            }
        }
    }
    for (int base = 64; base < d; base += 64) {  // rare: degree > 64
        int cnt = min(64, d - base);
        float w2 = 0.f; int s2 = 0;
        if (lane < cnt) { s2 = col[start + base + lane]; w2 = __expf(lrelu(as_[s2] + adi)) * inv; }
        int iters = (cnt + 7) >> 3;
        for (int it = 0; it < iters; it++) {
            int j = it * 8 + eg;
            float wj = __shfl(w2, j);
            int sj = __shfl(s2, j);
            if (j < cnt) {
                bf16x8 hv = *(const bf16x8*)&h[(size_t)sj * 64 + fq * 8];
                #pragma unroll
                for (int i = 0; i < 8; i++) acc[i] += wj * b2f(hv[i]);
            }
        }
    }
    #pragma unroll
    for (int off = 8; off < 64; off <<= 1)
        #pragma unroll
        for (int i = 0; i < 8; i++) acc[i] += __shfl_xor(acc[i], off);

    if (lane < 8) {
        unsigned int res[4];
        #pragma unroll
        for (int i = 0; i < 4; i++) {
            float o0 = acc[2 * i] + bias[fq * 8 + 2 * i];
            float o1 = acc[2 * i + 1] + bias[fq * 8 + 2 * i + 1];
            if (doElu) { o0 = eluf(o0); o1 = eluf(o1); }
            res[i] = (unsigned)f2bf(o0) | ((unsigned)f2bf(o1) << 16);
        }
        *(uint4*)&out[(size_t)wid * 64 + fq * 8] = *(uint4*)res;
    }
}

// ---------------- Aggregation F=16: bf16 gather, 2 lanes/row x 32 edge groups ----------------

__global__ __launch_bounds__(256) void k_agg16(
    const int* __restrict__ rowptr, const int* __restrict__ deg,
    const int* __restrict__ col, const float* __restrict__ as_,
    const float* __restrict__ ad_, const unsigned short* __restrict__ h,
    const float* __restrict__ bias, float* __restrict__ out, int N)
{
    int wid = (blockIdx.x * blockDim.x + threadIdx.x) >> 6;
    int lane = threadIdx.x & 63;
    if (wid >= N) return;
    int start = rowptr[wid];
    int d = deg[wid];
    float adi = ad_[wid];
    float eself = __expf(lrelu(as_[wid] + adi));

    int dc = min(d, 64);
    float w = 0.f; int s = 0;
    if (lane < dc) { s = col[start + lane]; w = __expf(lrelu(as_[s] + adi)); }
    float ssum = w;
    for (int j = lane + 64; j < d; j += 64)
        ssum += __expf(lrelu(as_[col[start + j]] + adi));
    #pragma unroll
    for (int off = 32; off; off >>= 1) ssum += __shfl_xor(ssum, off);
    float inv = 1.f / (ssum + eself + 1e-16f);
    w *= inv;

    int fq = lane & 1, eg = lane >> 1;
    float acc[8] = {0.f, 0.f, 0.f, 0.f, 0.f, 0.f, 0.f, 0.f};
    if (eg == 0) {
        bf16x8 hv = *(const bf16x8*)&h[(size_t)wid * 16 + fq * 8];
        float en = eself * inv;
        #pragma unroll
        for (int i = 0; i < 8; i++) acc[i] = en * b2f(hv[i]);
    }
    {
        int iters = (dc + 31) >> 5;
        for (int it = 0; it < iters; it++) {
            int j = it * 32 + eg;
            float wj = __shfl(w, j);
            int sj = __shfl(s, j);
            if (j < dc) {
                bf16x8 hv = *(const bf16x8*)&h[(size_t)sj * 16 + fq * 8];
                #pragma unroll
                for (int i = 0; i < 8; i++) acc[i] += wj * b2f(hv[i]);
            }
        }
    }
    for (int base = 64; base < d; base += 64) {
        int cnt = min(64, d - base);
        float w2 = 0.f; int s2 = 0;
        if (lane < cnt) { s2 = col[start + base + lane]; w2 = __expf(lrelu(as_[s2] + adi)) * inv; }
        int iters = (cnt + 31) >> 5;
        for (int it = 0; it < iters; it++) {
            int j = it * 32 + eg;
            float wj = __shfl(w2, j);
            int sj = __shfl(s2, j);
            if (j < cnt) {
                bf16x8 hv = *(const bf16x8*)&h[(size_t)sj * 16 + fq * 8];
                #pragma unroll
                for (int i = 0; i < 8; i++) acc[i] += wj * b2f(hv[i]);
            }
        }
    }
    #pragma unroll
    for (int off = 2; off < 64; off <<= 1)
        #pragma unroll
        for (int i = 0; i < 8; i++) acc[i] += __shfl_xor(acc[i], off);

    if (lane < 2) {
        float4 o0, o1;
        o0.x = acc[0] + bias[fq * 8 + 0]; o0.y = acc[1] + bias[fq * 8 + 1];
        o0.z = acc[2] + bias[fq * 8 + 2]; o0.w = acc[3] + bias[fq * 8 + 3];
        o1.x = acc[4] + bias[fq * 8 + 4]; o1.y = acc[5] + bias[fq * 8 + 5];
        o1.z = acc[6] + bias[fq * 8 + 6]; o1.w = acc[7] + bias[fq * 8 + 7];
        *(float4*)&out[(size_t)wid * 16 + fq * 8] = o0;
        *(float4*)&out[(size_t)wid * 16 + fq * 8 + 4] = o1;
    }
}

// ---------------- BatchNorm stats ----------------

__global__ __launch_bounds__(256) void k_bnstat(const float* __restrict__ logits,
                                                float* __restrict__ bn, int N) {
    int t = threadIdx.x;
    int c = t & 15;
    int g = (blockIdx.x * blockDim.x + t) >> 4;
    int stride = (gridDim.x * blockDim.x) >> 4;
    float s = 0.f, s2 = 0.f;
    for (int r = g; r < N; r += stride) {
        float v = logits[r * 16 + c];
        s += v;
        s2 += v * v;
    }
    s += __shfl_xor(s, 16);  s += __shfl_xor(s, 32);
    s2 += __shfl_xor(s2, 16); s2 += __shfl_xor(s2, 32);
    if ((t & 63) < 16) {
        atomicAdd(&bn[c], s);
        atomicAdd(&bn[16 + c], s2);
    }
}

// ---------------- BN apply + log_softmax + out (dtype-branched) ----------------

__global__ __launch_bounds__(256) void k_final(
    const float* __restrict__ logits, const float* __restrict__ bn,
    const float* __restrict__ gamma, const float* __restrict__ beta,
    const void* __restrict__ x1, void* __restrict__ out, int N)
{
    int f = detect_bf16(x1);
    int r = blockIdx.x * blockDim.x + threadIdx.x;
    if (r >= N) return;
    float invN = 1.f / (float)N;
    float y[16];
    float mx = -1e30f;
    #pragma unroll
    for (int c = 0; c < 16; c++) {
        float mu = bn[c] * invN;
        float var = bn[16 + c] * invN - mu * mu;
        float v = (logits[r * 16 + c] - mu) * rsqrtf(var + 1e-5f);
        v = v * gamma[c] + beta[c];
        y[c] = v;
        mx = fmaxf(mx, v);
    }
    float se = 0.f;
    #pragma unroll
    for (int c = 0; c < 16; c++) se += __expf(y[c] - mx);
    float lse = mx + __logf(se);
    #pragma unroll
    for (int c = 0; c < 16; c++) {
        float v = y[c] - lse;
        if (f) ((__hip_bfloat16*)out)[r * 16 + c] = __float2bfloat16(v);
        else   ((float*)out)[r * 16 + c] = v;
    }
}

// ---------------- launch ----------------

extern "C" void kernel_launch(void* const* d_in, const int* in_sizes, int n_in,
                              void* d_out, int out_size, void* d_ws, size_t ws_size,
                              hipStream_t stream) {
    const void* x1  = d_in[0];
    const void* x2  = d_in[1];
    const int*  ei1 = (const int*)d_in[2];
    const int*  ei2 = (const int*)d_in[3];

    const int N = in_sizes[0] / 64;
    const int E = in_sizes[2] / 2;
    const int nb = (N + 255) >> 8;
    const int NB = 2 * nb;
    const int chunk = (2 * E + NBLK - 1) / NBLK;

    char* p = (char*)d_ws;
    auto alloc = [&](size_t bytes) {
        void* q = (void*)p;
        p += (bytes + 255) & ~(size_t)255;
        return q;
    };
    float* bn       = (float*)alloc(256);                   // zeroed by memset
    unsigned short* h0 = (unsigned short*)alloc((size_t)N * 64 * 2);  // bf16
    unsigned short* h1 = (unsigned short*)alloc((size_t)N * 64 * 2);  // bf16
    unsigned short* hlin = (unsigned short*)alloc((size_t)N * 64 * 2); // bf16
    float* as_      = (float*)alloc((size_t)N * 4);
    float* ad_      = (float*)alloc((size_t)N * 4);
    int* rowptr1    = (int*)alloc((size_t)N * 4);
    int* deg1       = (int*)alloc((size_t)N * 4);
    int* rowptr2    = (int*)alloc((size_t)N * 4);
    int* deg2       = (int*)alloc((size_t)N * 4);
    int* col1       = (int*)alloc((size_t)nb * CAP * 4);    // aliased as logits later
    int* col2       = (int*)alloc((size_t)nb * CAP * 4);
    int* counts     = (int*)alloc((size_t)NB * NBLK * 4);
    int* bfill      = (int*)alloc((size_t)NB * 4);
    float* P        = (float*)alloc(P_TOTAL * 4);
    float* logits   = (float*)col1;  // col1 dead after layer-0 agg; nb*CAP*4 >= N*16*4

    // bedge (packed int) aliases h0/h1: NB*CAP*4 = 19.2MB <= 25.6MB contiguous;
    // consumed by k_bucket2 strictly before any h write.
    int* bedge   = (int*)h0;
    int* bedge2p = bedge + (size_t)nb * CAP;

    hipMemsetAsync(bn, 0, 256, stream);

    const int TB = 256;
    int gN = (N + TB - 1) / TB;
    int gW = (N + 3) / 4;
    int nt = (N + 63) / 64;
    int gT = nt < 512 ? nt : 512;

    Ptrs15 pp;
    pp.p[0] = d_in[4];  pp.p[1] = d_in[8];   pp.p[2] = d_in[12];
    pp.p[3] = d_in[5];  pp.p[4] = d_in[6];   pp.p[5] = d_in[7];
    pp.p[6] = d_in[9];  pp.p[7] = d_in[10];  pp.p[8] = d_in[11];
    pp.p[9] = d_in[13]; pp.p[10] = d_in[14]; pp.p[11] = d_in[15];
    pp.p[12] = d_in[16]; pp.p[13] = d_in[17]; pp.p[14] = x1;
    k_params<<<14, 256, 0, stream>>>(pp, P);

    // CSR build: count -> scan -> place -> per-bucket node sort
    k_count<<<NBLK, TB, 0, stream>>>(ei1, ei2, E, counts, nb, NB, chunk);
    k_scan<<<NB, TB, 0, stream>>>(counts, bfill);
    k_place<<<NBLK, TB, 0, stream>>>(ei1, ei2, E, counts, bedge, nb, NB, chunk);
    k_bucket2<<<NB, TB, 0, stream>>>(bfill, bedge, rowptr1, deg1, col1,
                                     bfill + nb, bedge2p, rowptr2, deg2, col2, nb, N);

    // Layer 0: x1 (raw) @ W0 -> hlin (bf16); aggregate graph1 -> h0 (elu, bf16)
    k_gemm_mfma<64, 64><<<gT, TB, 0, stream>>>(
        x1, 1, x1, 0, P + P_W0, P + P_AS0, P + P_AD0, hlin, as_, ad_, N, nt);
    k_agg64<<<gW, TB, 0, stream>>>(rowptr1, deg1, col1, as_, ad_, hlin, P + P_B0, h0, N, 1);

    // Layer 1: [h0 bf16 | x2 raw] @ W1 -> hlin; aggregate graph2 -> h1 (elu, bf16)
    k_gemm_mfma<128, 64><<<gT, TB, 0, stream>>>(
        h0, 0, x2, 1, P + P_W1, P + P_AS1, P + P_AD1, hlin, as_, ad_, N, nt);
    k_agg64<<<gW, TB, 0, stream>>>(rowptr2, deg2, col2, as_, ad_, hlin, P + P_B1, h1, N, 1);

    // Layer 2: [h0 | h1] @ W2 -> hlin(:,:16) bf16; aggregate graph2 -> logits (fp32)
    k_gemm_mfma<128, 16><<<gT, TB, 0, stream>>>(
        h0, 0, h1, 0, P + P_W2, P + P_AS2, P + P_AD2, hlin, as_, ad_, N, nt);
    k_agg16<<<gW, TB, 0, stream>>>(rowptr2, deg2, col2, as_, ad_, hlin, P + P_B2, logits, N);

    // BN + log_softmax
    k_bnstat<<<256, TB, 0, stream>>>(logits, bn, N);
    k_final<<<gN, TB, 0, stream>>>(logits, bn, P + P_GAMMA, P + P_BETA, x1, d_out, N);
}